// Round 10
// baseline (161.509 us; speedup 1.0000x reference)
//
#include <hip/hip_runtime.h>

#define NROWS 8192
#define KD    128
#define SQK1C 4.5398163f   /* sqrt(log2(e)/0.07); scaled ops make MFMA emit K1C*sim */

typedef __bf16 bf16x8 __attribute__((ext_vector_type(8)));
typedef float  f32x4  __attribute__((ext_vector_type(4)));

__device__ __forceinline__ unsigned short f2bf(float x) {
  unsigned int u = __builtin_bit_cast(unsigned int, x);
  unsigned int r = (u + 0x7FFFu + ((u >> 16) & 1u)) >> 16;  // RNE
  return (unsigned short)r;
}

// fp32 -> bf16 scaled by sqrt(K1C); zero the 4 sum arrays.
__global__ __launch_bounds__(256) void prep_kernel(const float4* __restrict__ F4,
                                                   const float4* __restrict__ M4,
                                                   ushort4* __restrict__ Fb4,
                                                   ushort4* __restrict__ Mb4,
                                                   float* __restrict__ sums) {
  int i = blockIdx.x * 256 + threadIdx.x;
  float4 f = F4[i];
  float4 m = M4[i];
  ushort4 fo, mo;
  fo.x = f2bf(f.x * SQK1C); fo.y = f2bf(f.y * SQK1C);
  fo.z = f2bf(f.z * SQK1C); fo.w = f2bf(f.w * SQK1C);
  mo.x = f2bf(m.x * SQK1C); mo.y = f2bf(m.y * SQK1C);
  mo.z = f2bf(m.z * SQK1C); mo.w = f2bf(m.w * SQK1C);
  Fb4[i] = fo;
  Mb4[i] = mo;
  if (i < 4 * NROWS) sums[i] = 0.0f;
}

// RACE-FREE BY CONSTRUCTION: no LDS, no __syncthreads anywhere in this kernel.
// Rounds 8/9 failed with ~10-ulp corruption whose magnitude analysis implicates a
// timing-dependent stale-LDS read (exp2 of self-sim-scale garbage); atomics were
// exonerated (lost-update bound ~1e-5). All operands are L2/LLC-resident (4MB bf16)
// so A and B fragments are read DIRECT from global into registers (bit-identical
// values to the LDS path; swizzle round-trip cancels).
// z=0(FM): rowsum->Spos_f, colsum->Spos_m (full). z=1(FF)/2(MM): upper triangle only;
// chunks ci<2by prefix-skipped; ci in {2by,2by+1} diag-zone (full compute, self-masked,
// rowsum only); ci>=2by+2 dual (rowsum[row] + mirror atomic into rowsum[col]).
// Dispatch order FF, MM, then uniform FM last (ragged work first, balanced tail).
// Quantum = 4 chunks (256 cols) per WG; empty WGs return before any loads.
__global__ __launch_bounds__(256, 3) void gemm_kernel(const unsigned short* __restrict__ Fb,
                                                      const unsigned short* __restrict__ Mb,
                                                      float* __restrict__ sums) {
  const int gx = blockIdx.x;             // 0..31  group of 4 chunks (256 cols)
  const int by = blockIdx.y;             // 0..63  row block (128 rows)
  const int z  = (blockIdx.z + 1) % 3;   // dispatch order: FF, MM, then FM
  const int R  = by * 128;

  int i0 = 0;
  if (z > 0) {
    const int d = 2 * by - 4 * gx;       // first valid local chunk index
    if (d > 3) return;                   // whole group strictly below diagonal
    i0 = (d > 0) ? d : 0;
  }

  const unsigned short* A;
  const unsigned short* B;
  float* rowsum;
  float* colsum = nullptr;
  if (z == 0)      { A = Fb; B = Mb; rowsum = sums;             colsum = sums + NROWS; }
  else if (z == 1) { A = Fb; B = Fb; rowsum = sums + 2 * NROWS; }
  else             { A = Mb; B = Mb; rowsum = sums + 3 * NROWS; }
  float* cbase = (z == 0) ? colsum : rowsum;   // mirror target for sym dual chunks

  const int lane = threadIdx.x & 63;
  const int wave = threadIdx.x >> 6;     // 0..3
  const int wr = wave >> 1, wc = wave & 1;
  const int l15 = lane & 15, l4 = lane >> 4;   // l4 in 0..3

  // ---- A fragments direct from global (L2-resident). 16x16x32 A-operand map:
  // af[m][k] = A[row = R + wr*64 + m*16 + l15][kcol = k*32 + l4*8 + e]
  bf16x8 af[4][4];
  {
    const unsigned short* ap = A + (size_t)(R + wr * 64 + l15) * KD + l4 * 8;
    #pragma unroll
    for (int m = 0; m < 4; ++m)
      #pragma unroll
      for (int k = 0; k < 4; ++k)
        af[m][k] = *(const bf16x8*)(ap + (size_t)m * 16 * KD + k * 32);
  }

  float rowacc[16];
  #pragma unroll
  for (int i = 0; i < 16; ++i) rowacc[i] = 0.f;

  const f32x4 zero4 = {};
  // B fragment base: row = ci*64 + wc*32 + l15 (+16 for nb=1), kcol = k*32 + l4*8
  const unsigned short* bq0 = B + (size_t)(gx * 256 + wc * 32 + l15) * KD + l4 * 8;

  for (int i = i0; i < 4; ++i) {
    const int ci = gx * 4 + i;              // global chunk (64 cols)
    const unsigned short* bq = bq0 + (size_t)i * 64 * KD;

    f32x4 acc[4][2];
    #pragma unroll
    for (int k = 0; k < 4; ++k) {
      bf16x8 b0 = *(const bf16x8*)(bq + k * 32);
      bf16x8 b1 = *(const bf16x8*)(bq + 16 * KD + k * 32);
      #pragma unroll
      for (int m = 0; m < 4; ++m) {
        acc[m][0] = __builtin_amdgcn_mfma_f32_16x16x32_bf16(af[m][k], b0,
                       k ? acc[m][0] : zero4, 0, 0, 0);
        acc[m][1] = __builtin_amdgcn_mfma_f32_16x16x32_bf16(af[m][k], b1,
                       k ? acc[m][1] : zero4, 0, 0, 0);
      }
    }

    // Epilogue: v = exp2(K1C*sim).
    const int  C    = ci * 64;                        // chunk col base
    const bool dual = (z == 0) || (ci >= 2 * by + 2); // needs col accumulation
    if (dual) {
      float ca0 = 0.f, ca1 = 0.f;
      #pragma unroll
      for (int m = 0; m < 4; ++m) {
        #pragma unroll
        for (int j = 0; j < 4; ++j) {
          float v0 = __builtin_amdgcn_exp2f(acc[m][0][j]);
          float v1 = __builtin_amdgcn_exp2f(acc[m][1][j]);
          rowacc[m * 4 + j] += v0 + v1;
          ca0 += v0; ca1 += v1;
        }
      }
      ca0 += __shfl_xor(ca0, 16);
      ca0 += __shfl_xor(ca0, 32);
      ca1 += __shfl_xor(ca1, 16);
      ca1 += __shfl_xor(ca1, 32);
      if (l4 == 0) {
        float* cp = cbase + C + wc * 32 + l15;
        unsafeAtomicAdd(cp, ca0);
        unsafeAtomicAdd(cp + 16, ca1);
      }
    } else {
      // diagonal-zone chunk of a symmetric GEMM: mask self-sim, rowsum only
      #pragma unroll
      for (int m = 0; m < 4; ++m) {
        #pragma unroll
        for (int j = 0; j < 4; ++j) {
          float v0 = __builtin_amdgcn_exp2f(acc[m][0][j]);
          float v1 = __builtin_amdgcn_exp2f(acc[m][1][j]);
          const int grow = R + wr * 64 + m * 16 + l4 * 4 + j;   // C/D: row=(l>>4)*4+j
          const int gcol = C + wc * 32 + l15;                   //      col=l&15
          if (grow == gcol)      v0 = 0.f;
          if (grow == gcol + 16) v1 = 0.f;
          rowacc[m * 4 + j] += v0 + v1;
        }
      }
    }
  }

  // rowsum flush: butterfly over l15 (cols), 4 lanes/wave do the atomics.
  #pragma unroll
  for (int i = 0; i < 16; ++i) {
    float v = rowacc[i];
    v += __shfl_xor(v, 1);
    v += __shfl_xor(v, 2);
    v += __shfl_xor(v, 4);
    v += __shfl_xor(v, 8);
    rowacc[i] = v;
  }
  if (l15 == 0) {
    const int rbase = R + wr * 64 + l4 * 4;
    #pragma unroll
    for (int i = 0; i < 16; ++i)
      unsafeAtomicAdd(rowsum + rbase + (i >> 2) * 16 + (i & 3), rowacc[i]);
  }
}

// loss = 1.5*mean(log1p(Sneg_f/Spos_f)) + 0.5*mean(log1p(Sneg_m/Spos_m))
// (uniform 2^{-K1C} factor cancels in the ratios)
__global__ __launch_bounds__(1024) void loss_kernel(const float* __restrict__ sums,
                                                    float* __restrict__ out) {
  const float* Spf = sums;
  const float* Spm = sums + NROWS;
  const float* Snf = sums + 2 * NROWS;
  const float* Snm = sums + 3 * NROWS;
  float accf = 0.f, accm = 0.f;
  for (int i = threadIdx.x; i < NROWS; i += 1024) {
    accf += log1pf(Snf[i] / Spf[i]);
    accm += log1pf(Snm[i] / Spm[i]);
  }
  float v = 1.5f * accf + 0.5f * accm;
  #pragma unroll
  for (int s = 1; s < 64; s <<= 1) v += __shfl_xor(v, s);
  __shared__ float red[16];
  if ((threadIdx.x & 63) == 0) red[threadIdx.x >> 6] = v;
  __syncthreads();
  if (threadIdx.x == 0) {
    float s = 0.f;
    #pragma unroll
    for (int i = 0; i < 16; ++i) s += red[i];
    out[0] = s * (1.0f / NROWS);
  }
}

extern "C" void kernel_launch(void* const* d_in, const int* in_sizes, int n_in,
                              void* d_out, int out_size, void* d_ws, size_t ws_size,
                              hipStream_t stream) {
  (void)in_sizes; (void)n_in; (void)out_size; (void)ws_size;
  const float* F = (const float*)d_in[0];
  const float* M = (const float*)d_in[1];
  float* out = (float*)d_out;

  float* sums = (float*)d_ws;
  unsigned short* Fb = (unsigned short*)((char*)d_ws + 4 * NROWS * sizeof(float));
  unsigned short* Mb = Fb + (size_t)NROWS * KD;

  prep_kernel<<<dim3(NROWS * KD / 4 / 256), dim3(256), 0, stream>>>(
      (const float4*)F, (const float4*)M, (ushort4*)Fb, (ushort4*)Mb, sums);
  gemm_kernel<<<dim3(32, 64, 3), dim3(256), 0, stream>>>(Fb, Mb, sums);
  loss_kernel<<<dim3(1), dim3(1024), 0, stream>>>(sums, out);
}

// Round 11
// 143.502 us; speedup vs baseline: 1.1255x; 1.1255x over previous
//
#include <hip/hip_runtime.h>

#define NROWS 8192
#define KD    128
#define SQK1C 4.5398163f   /* sqrt(log2(e)/0.07); scaled ops make MFMA emit K1C*sim */

typedef __bf16 bf16x8 __attribute__((ext_vector_type(8)));
typedef float  f32x4  __attribute__((ext_vector_type(4)));

__device__ __forceinline__ unsigned short f2bf(float x) {
  unsigned int u = __builtin_bit_cast(unsigned int, x);
  unsigned int r = (u + 0x7FFFu + ((u >> 16) & 1u)) >> 16;  // RNE
  return (unsigned short)r;
}

// fp32 -> bf16 scaled by sqrt(K1C); zero the 4 sum arrays.
__global__ __launch_bounds__(256) void prep_kernel(const float4* __restrict__ F4,
                                                   const float4* __restrict__ M4,
                                                   ushort4* __restrict__ Fb4,
                                                   ushort4* __restrict__ Mb4,
                                                   float* __restrict__ sums) {
  int i = blockIdx.x * 256 + threadIdx.x;
  float4 f = F4[i];
  float4 m = M4[i];
  ushort4 fo, mo;
  fo.x = f2bf(f.x * SQK1C); fo.y = f2bf(f.y * SQK1C);
  fo.z = f2bf(f.z * SQK1C); fo.w = f2bf(f.w * SQK1C);
  mo.x = f2bf(m.x * SQK1C); mo.y = f2bf(m.y * SQK1C);
  mo.z = f2bf(m.z * SQK1C); mo.w = f2bf(m.w * SQK1C);
  Fb4[i] = fo;
  Mb4[i] = mo;
  if (i < 4 * NROWS) sums[i] = 0.0f;
}

// RACE-FREE BY CONSTRUCTION (round-10): no LDS, no __syncthreads. All operands
// L2-resident (4MB total); A and B fragments read direct from global into regs.
// ROUND-11 FIX for r10's latency serialization (MfmaUtil 9.4%, 78% stall):
// register-level software pipeline — next chunk's 8 B-fragments (bn) are issued
// BEFORE the current chunk's MFMA cluster; 32 MFMAs + epilogue (~1000 cyc) cover
// the ~600-cyc L2 latency; bc<-bn is an SSA rename (static indices, rule #20).
// z=0(FM): rowsum->Spos_f, colsum->Spos_m (full). z=1(FF)/2(MM): upper triangle;
// chunks ci<2by prefix-skipped; ci in {2by,2by+1} diag-zone (self-masked, rowsum
// only); ci>=2by+2 dual (rowsum[row] + mirror atomic into rowsum[col]).
// Dispatch order FF, MM (ragged) first, uniform FM last. Quantum = 8 chunks.
// launch_bounds(256,2): VGPR cap 256 >> ~190 need -> guaranteed no spill.
__global__ __launch_bounds__(256, 2) void gemm_kernel(const unsigned short* __restrict__ Fb,
                                                      const unsigned short* __restrict__ Mb,
                                                      float* __restrict__ sums) {
  const int gx = blockIdx.x;             // 0..15  group of 8 chunks (512 cols)
  const int by = blockIdx.y;             // 0..63  row block (128 rows)
  const int z  = (blockIdx.z + 1) % 3;   // dispatch order: FF, MM, then FM
  const int R  = by * 128;

  int i0 = 0;
  if (z > 0) {
    const int d = 2 * by - 8 * gx;       // first valid local chunk index
    if (d > 7) return;                   // whole group strictly below diagonal
    i0 = (d > 0) ? d : 0;
  }

  const unsigned short* A;
  const unsigned short* B;
  float* rowsum;
  float* colsum = nullptr;
  if (z == 0)      { A = Fb; B = Mb; rowsum = sums;             colsum = sums + NROWS; }
  else if (z == 1) { A = Fb; B = Fb; rowsum = sums + 2 * NROWS; }
  else             { A = Mb; B = Mb; rowsum = sums + 3 * NROWS; }
  float* cbase = (z == 0) ? colsum : rowsum;   // mirror target for sym dual chunks

  const int lane = threadIdx.x & 63;
  const int wave = threadIdx.x >> 6;     // 0..3
  const int wr = wave >> 1, wc = wave & 1;
  const int l15 = lane & 15, l4 = lane >> 4;   // l4 in 0..3

  // ---- A fragments direct from global (L2-resident). 16x16x32 A-operand map:
  // af[m][k] = A[row = R + wr*64 + m*16 + l15][kcol = k*32 + l4*8 + e]
  bf16x8 af[4][4];
  {
    const unsigned short* ap = A + (size_t)(R + wr * 64 + l15) * KD + l4 * 8;
    #pragma unroll
    for (int m = 0; m < 4; ++m)
      #pragma unroll
      for (int k = 0; k < 4; ++k)
        af[m][k] = *(const bf16x8*)(ap + (size_t)m * 16 * KD + k * 32);
  }

  float rowacc[16];
  #pragma unroll
  for (int i = 0; i < 16; ++i) rowacc[i] = 0.f;

  const f32x4 zero4 = {};
  // B fragment base: row = ci*64 + wc*32 + l15 (+16 for the upper 16-col half),
  // kcol = k*32 + l4*8. bc[k] = b0 (cols C..C+15), bc[4+k] = b1 (cols C+16..C+31... +wc*32)
  const unsigned short* bq0 = B + (size_t)(gx * 512 + wc * 32 + l15) * KD + l4 * 8;

  // Prime the pipeline: chunk i0's 8 fragments.
  bf16x8 bc[8];
  {
    const unsigned short* bq = bq0 + (size_t)i0 * 64 * KD;
    #pragma unroll
    for (int k = 0; k < 4; ++k) {
      bc[k]     = *(const bf16x8*)(bq + k * 32);
      bc[4 + k] = *(const bf16x8*)(bq + 16 * KD + k * 32);
    }
  }

  for (int i = i0; i < 8; ++i) {
    // Issue NEXT chunk's loads first — latency hides under this chunk's MFMA+epilogue.
    bf16x8 bn[8];
    if (i < 7) {
      const unsigned short* bqn = bq0 + (size_t)(i + 1) * 64 * KD;
      #pragma unroll
      for (int k = 0; k < 4; ++k) {
        bn[k]     = *(const bf16x8*)(bqn + k * 32);
        bn[4 + k] = *(const bf16x8*)(bqn + 16 * KD + k * 32);
      }
    }

    const int ci = gx * 8 + i;              // global chunk (64 cols)
    f32x4 acc[4][2];
    #pragma unroll
    for (int k = 0; k < 4; ++k) {
      #pragma unroll
      for (int m = 0; m < 4; ++m) {
        acc[m][0] = __builtin_amdgcn_mfma_f32_16x16x32_bf16(af[m][k], bc[k],
                       k ? acc[m][0] : zero4, 0, 0, 0);
        acc[m][1] = __builtin_amdgcn_mfma_f32_16x16x32_bf16(af[m][k], bc[4 + k],
                       k ? acc[m][1] : zero4, 0, 0, 0);
      }
    }

    // Epilogue: v = exp2(K1C*sim).
    const int  C    = ci * 64;                        // chunk col base
    const bool dual = (z == 0) || (ci >= 2 * by + 2); // needs col accumulation
    if (dual) {
      float ca0 = 0.f, ca1 = 0.f;
      #pragma unroll
      for (int m = 0; m < 4; ++m) {
        #pragma unroll
        for (int j = 0; j < 4; ++j) {
          float v0 = __builtin_amdgcn_exp2f(acc[m][0][j]);
          float v1 = __builtin_amdgcn_exp2f(acc[m][1][j]);
          rowacc[m * 4 + j] += v0 + v1;
          ca0 += v0; ca1 += v1;
        }
      }
      ca0 += __shfl_xor(ca0, 16);
      ca0 += __shfl_xor(ca0, 32);
      ca1 += __shfl_xor(ca1, 16);
      ca1 += __shfl_xor(ca1, 32);
      if (l4 == 0) {
        float* cp = cbase + C + wc * 32 + l15;
        unsafeAtomicAdd(cp, ca0);
        unsafeAtomicAdd(cp + 16, ca1);
      }
    } else {
      // diagonal-zone chunk of a symmetric GEMM: mask self-sim, rowsum only
      #pragma unroll
      for (int m = 0; m < 4; ++m) {
        #pragma unroll
        for (int j = 0; j < 4; ++j) {
          float v0 = __builtin_amdgcn_exp2f(acc[m][0][j]);
          float v1 = __builtin_amdgcn_exp2f(acc[m][1][j]);
          const int grow = R + wr * 64 + m * 16 + l4 * 4 + j;   // C/D: row=(l>>4)*4+j
          const int gcol = C + wc * 32 + l15;                   //      col=l&15
          if (grow == gcol)      v0 = 0.f;
          if (grow == gcol + 16) v1 = 0.f;
          rowacc[m * 4 + j] += v0 + v1;
        }
      }
    }

    // Rotate pipeline (SSA rename; static indices -> stays in registers).
    #pragma unroll
    for (int q = 0; q < 8; ++q) bc[q] = bn[q];
  }

  // rowsum flush: butterfly over l15 (cols), 4 lanes/wave do the atomics.
  #pragma unroll
  for (int i = 0; i < 16; ++i) {
    float v = rowacc[i];
    v += __shfl_xor(v, 1);
    v += __shfl_xor(v, 2);
    v += __shfl_xor(v, 4);
    v += __shfl_xor(v, 8);
    rowacc[i] = v;
  }
  if (l15 == 0) {
    const int rbase = R + wr * 64 + l4 * 4;
    #pragma unroll
    for (int i = 0; i < 16; ++i)
      unsafeAtomicAdd(rowsum + rbase + (i >> 2) * 16 + (i & 3), rowacc[i]);
  }
}

// loss = 1.5*mean(log1p(Sneg_f/Spos_f)) + 0.5*mean(log1p(Sneg_m/Spos_m))
// (uniform 2^{-K1C} factor cancels in the ratios)
__global__ __launch_bounds__(1024) void loss_kernel(const float* __restrict__ sums,
                                                    float* __restrict__ out) {
  const float* Spf = sums;
  const float* Spm = sums + NROWS;
  const float* Snf = sums + 2 * NROWS;
  const float* Snm = sums + 3 * NROWS;
  float accf = 0.f, accm = 0.f;
  for (int i = threadIdx.x; i < NROWS; i += 1024) {
    accf += log1pf(Snf[i] / Spf[i]);
    accm += log1pf(Snm[i] / Spm[i]);
  }
  float v = 1.5f * accf + 0.5f * accm;
  #pragma unroll
  for (int s = 1; s < 64; s <<= 1) v += __shfl_xor(v, s);
  __shared__ float red[16];
  if ((threadIdx.x & 63) == 0) red[threadIdx.x >> 6] = v;
  __syncthreads();
  if (threadIdx.x == 0) {
    float s = 0.f;
    #pragma unroll
    for (int i = 0; i < 16; ++i) s += red[i];
    out[0] = s * (1.0f / NROWS);
  }
}

extern "C" void kernel_launch(void* const* d_in, const int* in_sizes, int n_in,
                              void* d_out, int out_size, void* d_ws, size_t ws_size,
                              hipStream_t stream) {
  (void)in_sizes; (void)n_in; (void)out_size; (void)ws_size;
  const float* F = (const float*)d_in[0];
  const float* M = (const float*)d_in[1];
  float* out = (float*)d_out;

  float* sums = (float*)d_ws;
  unsigned short* Fb = (unsigned short*)((char*)d_ws + 4 * NROWS * sizeof(float));
  unsigned short* Mb = Fb + (size_t)NROWS * KD;

  prep_kernel<<<dim3(NROWS * KD / 4 / 256), dim3(256), 0, stream>>>(
      (const float4*)F, (const float4*)M, (ushort4*)Fb, (ushort4*)Mb, sums);
  gemm_kernel<<<dim3(16, 64, 3), dim3(256), 0, stream>>>(Fb, Mb, sums);
  loss_kernel<<<dim3(1), dim3(1024), 0, stream>>>(sums, out);
}

// Round 12
// 135.320 us; speedup vs baseline: 1.1935x; 1.0605x over previous
//
#include <hip/hip_runtime.h>

#define NROWS 8192
#define KD    128
#define SQK1C 4.5398163f   /* sqrt(log2(e)/0.07); scaled ops make MFMA emit K1C*sim */

typedef __bf16 bf16x8 __attribute__((ext_vector_type(8)));
typedef float  f32x4  __attribute__((ext_vector_type(4)));

__device__ __forceinline__ unsigned short f2bf(float x) {
  unsigned int u = __builtin_bit_cast(unsigned int, x);
  unsigned int r = (u + 0x7FFFu + ((u >> 16) & 1u)) >> 16;  // RNE
  return (unsigned short)r;
}

// fp32 -> bf16 scaled by sqrt(K1C); zero the 4 sum arrays.
__global__ __launch_bounds__(256) void prep_kernel(const float4* __restrict__ F4,
                                                   const float4* __restrict__ M4,
                                                   ushort4* __restrict__ Fb4,
                                                   ushort4* __restrict__ Mb4,
                                                   float* __restrict__ sums) {
  int i = blockIdx.x * 256 + threadIdx.x;
  float4 f = F4[i];
  float4 m = M4[i];
  ushort4 fo, mo;
  fo.x = f2bf(f.x * SQK1C); fo.y = f2bf(f.y * SQK1C);
  fo.z = f2bf(f.z * SQK1C); fo.w = f2bf(f.w * SQK1C);
  mo.x = f2bf(m.x * SQK1C); mo.y = f2bf(m.y * SQK1C);
  mo.z = f2bf(m.z * SQK1C); mo.w = f2bf(m.w * SQK1C);
  Fb4[i] = fo;
  Mb4[i] = mo;
  if (i < 4 * NROWS) sums[i] = 0.0f;
}

// r5 tiling (best clean baseline: 67us gemm) with two changes:
// 1) A fragments DIRECT from global into regs (race-impossible reads of read-only
//    data; removes the A-LDS prologue and both its barriers). r10/r11-proven values.
// 2) B staging is REG-STAGED (global->VGPR->ds_write(swizzled)->barrier->ds_read):
//    no global_load_lds async-DMA semantics (implicated in r7/r8/r9 corruption).
//    T14 issue-early/write-late: gload c_{t+3} issues at end of iter t, ds_write at
//    end of iter t+1 -> a full iteration of latency cover; ONE barrier per chunk.
// z=0: FM (rowsum->Spos_f, colsum->Spos_m). z=1: FF, z=2: MM (full compute, diag
// masked). No triangle this round (isolate the new staging mechanism).
__global__ __launch_bounds__(256, 3) void gemm_kernel(const unsigned short* __restrict__ Fb,
                                                      const unsigned short* __restrict__ Mb,
                                                      float* __restrict__ sums) {
  __shared__ __align__(16) unsigned short lds[2][64 * KD];  // 2 x 16KB (B only)

  const int bx = blockIdx.x;   // 0..7   col strip (1024)
  const int by = blockIdx.y;   // 0..63  row block (128)
  const int z  = blockIdx.z;   // 0..2
  const int R  = by * 128;

  const unsigned short* A;
  const unsigned short* B;
  float* rowsum;
  float* colsum = nullptr;
  if (z == 0)      { A = Fb; B = Mb; rowsum = sums;             colsum = sums + NROWS; }
  else if (z == 1) { A = Fb; B = Fb; rowsum = sums + 2 * NROWS; }
  else             { A = Mb; B = Mb; rowsum = sums + 3 * NROWS; }

  const int tid  = threadIdx.x;
  const int lane = tid & 63;
  const int wave = tid >> 6;          // 0..3
  const int wr = wave >> 1, wc = wave & 1;
  const int l15 = lane & 15, l4 = lane >> 4;

  // ---- A fragments direct from global (L2-resident). 16x16x32 A-operand map:
  // af[m][k] = A[row = R + wr*64 + m*16 + l15][kcol = k*32 + l4*8 + e]
  bf16x8 af[4][4];
  {
    const unsigned short* ap = A + (size_t)(R + wr * 64 + l15) * KD + l4 * 8;
    #pragma unroll
    for (int m = 0; m < 4; ++m)
      #pragma unroll
      for (int k = 0; k < 4; ++k)
        af[m][k] = *(const bf16x8*)(ap + (size_t)m * 16 * KD + k * 32);
  }

  // ---- B staging: 16KB chunk = 64 rows x 256B. Thread owns 4 x 16B pieces at
  // linear byte lin_i = tid*16 + i*4096. Global read is LINEAR (coalesced);
  // ds_write applies the XOR swizzle; ds_read uses the same XOR -> consistent.
  const char* Bbase = (const char*)(B + (size_t)bx * 1024 * KD);
  int swaddr[4];        // loop-invariant swizzled LDS byte offsets
  #pragma unroll
  for (int i = 0; i < 4; ++i) {
    const int lin = tid * 16 + i * 4096;
    const int row = lin >> 8;
    swaddr[i] = row * 256 + ((lin & 255) ^ ((row & 7) << 4));
  }

  float4 sreg[4];
#define GLOAD(t) do {                                                              \
    const char* s_ = Bbase + (size_t)(t) * 16384;                                  \
    _Pragma("unroll")                                                              \
    for (int i_ = 0; i_ < 4; ++i_)                                                 \
      sreg[i_] = *(const float4*)(s_ + tid * 16 + i_ * 4096);                      \
  } while (0)
#define SWRITE(buf) do {                                                           \
    _Pragma("unroll")                                                              \
    for (int i_ = 0; i_ < 4; ++i_)                                                 \
      *(float4*)((char*)(buf) + swaddr[i_]) = sreg[i_];                            \
  } while (0)

  // Prologue: buf0<-c0, buf1<-c1, c2 in flight in sreg.
  GLOAD(0); SWRITE(lds[0]);
  GLOAD(1); SWRITE(lds[1]);
  GLOAD(2);
  __syncthreads();

  float rowacc[16];
  #pragma unroll
  for (int i = 0; i < 16; ++i) rowacc[i] = 0.f;

  const int brow0 = wc * 32 + l15;          // B-row in chunk (out col); +16 for n=1
  const int bsw   = (brow0 & 7) << 4;       // (brow0+16)&7 == brow0&7
  const f32x4 zero4 = {};

  for (int t = 0; t < 16; ++t) {
    const char* pb0 = (const char*)lds[t & 1] + brow0 * 256;

    f32x4 acc[4][2];
    __builtin_amdgcn_s_setprio(1);
    #pragma unroll
    for (int k = 0; k < 4; ++k) {
      const int c = (k * 64 + l4 * 16) ^ bsw;
      bf16x8 b0 = *(const bf16x8*)(pb0 + c);
      bf16x8 b1 = *(const bf16x8*)(pb0 + 16 * 256 + c);
      #pragma unroll
      for (int m = 0; m < 4; ++m) {
        acc[m][0] = __builtin_amdgcn_mfma_f32_16x16x32_bf16(af[m][k], b0,
                       k ? acc[m][0] : zero4, 0, 0, 0);
        acc[m][1] = __builtin_amdgcn_mfma_f32_16x16x32_bf16(af[m][k], b1,
                       k ? acc[m][1] : zero4, 0, 0, 0);
      }
    }
    __builtin_amdgcn_s_setprio(0);

    // Epilogue: v = exp2(K1C*sim); rowacc in regs; colsum (z==0) lane-local + atomic.
    const bool diag = (z > 0) && ((((bx << 4) + t) >> 1) == by);
    if (z == 0) {
      float ca0 = 0.f, ca1 = 0.f;
      #pragma unroll
      for (int m = 0; m < 4; ++m) {
        #pragma unroll
        for (int j = 0; j < 4; ++j) {
          float v0 = __builtin_amdgcn_exp2f(acc[m][0][j]);
          float v1 = __builtin_amdgcn_exp2f(acc[m][1][j]);
          rowacc[m * 4 + j] += v0 + v1;
          ca0 += v0; ca1 += v1;
        }
      }
      ca0 += __shfl_xor(ca0, 16);
      ca0 += __shfl_xor(ca0, 32);
      ca1 += __shfl_xor(ca1, 16);
      ca1 += __shfl_xor(ca1, 32);
      if (l4 == 0) {
        float* cp = colsum + bx * 1024 + t * 64 + wc * 32 + l15;
        unsafeAtomicAdd(cp, ca0);
        unsafeAtomicAdd(cp + 16, ca1);
      }
    } else {
      #pragma unroll
      for (int m = 0; m < 4; ++m) {
        #pragma unroll
        for (int j = 0; j < 4; ++j) {
          float v0 = __builtin_amdgcn_exp2f(acc[m][0][j]);
          float v1 = __builtin_amdgcn_exp2f(acc[m][1][j]);
          if (diag) {
            const int grow = R + wr * 64 + m * 16 + l4 * 4 + j;   // C/D: row=(l>>4)*4+j
            const int gcol = bx * 1024 + t * 64 + wc * 32 + l15;  //      col=l&15
            if (grow == gcol)      v0 = 0.f;
            if (grow == gcol + 16) v1 = 0.f;
          }
          rowacc[m * 4 + j] += v0 + v1;
        }
      }
    }

    __syncthreads();                    // all waves done reading lds[t&1]; prior
                                        // ds_writes drained (lgkmcnt at barrier)
    if (t + 2 < 16) SWRITE(lds[t & 1]); // c_{t+2} (loaded end of t-1) -> vacated buf
    if (t + 3 < 16) GLOAD(t + 3);       // issue-early; consumed end of t+1
  }
#undef GLOAD
#undef SWRITE

  // rowsum flush: butterfly over l15 (cols), 4 lanes/wave do the atomics.
  #pragma unroll
  for (int i = 0; i < 16; ++i) {
    float v = rowacc[i];
    v += __shfl_xor(v, 1);
    v += __shfl_xor(v, 2);
    v += __shfl_xor(v, 4);
    v += __shfl_xor(v, 8);
    rowacc[i] = v;
  }
  if (l15 == 0) {
    const int rbase = R + wr * 64 + l4 * 4;
    #pragma unroll
    for (int i = 0; i < 16; ++i)
      unsafeAtomicAdd(rowsum + rbase + (i >> 2) * 16 + (i & 3), rowacc[i]);
  }
}

// loss = 1.5*mean(log1p(Sneg_f/Spos_f)) + 0.5*mean(log1p(Sneg_m/Spos_m))
// (uniform 2^{-K1C} factor cancels in the ratios)
__global__ __launch_bounds__(1024) void loss_kernel(const float* __restrict__ sums,
                                                    float* __restrict__ out) {
  const float* Spf = sums;
  const float* Spm = sums + NROWS;
  const float* Snf = sums + 2 * NROWS;
  const float* Snm = sums + 3 * NROWS;
  float accf = 0.f, accm = 0.f;
  for (int i = threadIdx.x; i < NROWS; i += 1024) {
    accf += log1pf(Snf[i] / Spf[i]);
    accm += log1pf(Snm[i] / Spm[i]);
  }
  float v = 1.5f * accf + 0.5f * accm;
  #pragma unroll
  for (int s = 1; s < 64; s <<= 1) v += __shfl_xor(v, s);
  __shared__ float red[16];
  if ((threadIdx.x & 63) == 0) red[threadIdx.x >> 6] = v;
  __syncthreads();
  if (threadIdx.x == 0) {
    float s = 0.f;
    #pragma unroll
    for (int i = 0; i < 16; ++i) s += red[i];
    out[0] = s * (1.0f / NROWS);
  }
}

extern "C" void kernel_launch(void* const* d_in, const int* in_sizes, int n_in,
                              void* d_out, int out_size, void* d_ws, size_t ws_size,
                              hipStream_t stream) {
  (void)in_sizes; (void)n_in; (void)out_size; (void)ws_size;
  const float* F = (const float*)d_in[0];
  const float* M = (const float*)d_in[1];
  float* out = (float*)d_out;

  float* sums = (float*)d_ws;
  unsigned short* Fb = (unsigned short*)((char*)d_ws + 4 * NROWS * sizeof(float));
  unsigned short* Mb = Fb + (size_t)NROWS * KD;

  prep_kernel<<<dim3(NROWS * KD / 4 / 256), dim3(256), 0, stream>>>(
      (const float4*)F, (const float4*)M, (ushort4*)Fb, (ushort4*)Mb, sums);
  gemm_kernel<<<dim3(8, 64, 3), dim3(256), 0, stream>>>(Fb, Mb, sums);
  loss_kernel<<<dim3(1), dim3(1024), 0, stream>>>(sums, out);
}